// Round 8
// baseline (898.303 us; speedup 1.0000x reference)
//
#include <hip/hip_runtime.h>
#include <math.h>

#define NS 200
#define FEAT 64
#define GRIDN 128

__device__ __forceinline__ float rl(float v, int l) {
    return __uint_as_float(
        __builtin_amdgcn_readlane(__float_as_uint(v), (unsigned)l));
}

__device__ __forceinline__ float trilinear(const float* __restrict__ g,
                                           float x, float y, float z) {
    const float W = 128.f, H = 128.f, D = 128.f;
    float gx = ((x + 1.f) * W - 1.f) * 0.5f;
    float gy = ((y + 1.f) * H - 1.f) * 0.5f;
    float gz = ((z + 1.f) * D - 1.f) * 0.5f;
    float x0 = floorf(gx), y0 = floorf(gy), z0 = floorf(gz);
    float out = 0.f;
#pragma unroll
    for (int dz = 0; dz < 2; ++dz)
#pragma unroll
        for (int dy = 0; dy < 2; ++dy)
#pragma unroll
            for (int dx = 0; dx < 2; ++dx) {
                float xi = x0 + dx, yi = y0 + dy, zi = z0 + dz;
                float w = (1.f - fabsf(gx - xi)) * (1.f - fabsf(gy - yi)) *
                          (1.f - fabsf(gz - zi));
                bool valid = (xi >= 0.f) && (xi < W) && (yi >= 0.f) &&
                             (yi < H) && (zi >= 0.f) && (zi < D);
                int xc = (int)fminf(fmaxf(xi, 0.f), 127.f);
                int yc = (int)fminf(fmaxf(yi, 0.f), 127.f);
                int zc = (int)fminf(fmaxf(zi, 0.f), 127.f);
                float v = valid ? g[(zc * GRIDN + yc) * GRIDN + xc] : 0.f;
                out += w * v;
            }
    return out;
}

// ws usage: ONLY 65 floats. ws[0..63] = w2s = fw2@sw ; ws[64] = fb2@sw + sb
__global__ __launch_bounds__(128) void precomp(const float* __restrict__ fw2,
                                               const float* __restrict__ sw,
                                               const float* __restrict__ fb2,
                                               const float* __restrict__ sb,
                                               float* __restrict__ ws) {
    int tid = threadIdx.x;
    if (tid < FEAT) {
        float a = 0.f;
        for (int j = 0; j < FEAT; ++j) a += fw2[tid * FEAT + j] * sw[j];
        ws[tid] = a;
    } else if (tid == FEAT) {
        float a = sb[0];
        for (int j = 0; j < FEAT; ++j) a += fb2[j] * sw[j];
        ws[FEAT] = a;
    }
}

__global__ __launch_bounds__(256, 8) void render(
    const float* __restrict__ ro, const float* __restrict__ rd,
    const float* __restrict__ gvol, const float* __restrict__ aabb,
    const float* __restrict__ fw1, const float* __restrict__ fb1,
    const float* __restrict__ fw2, const float* __restrict__ fb2,
    const float* __restrict__ rw1, const float* __restrict__ rb1,
    const float* __restrict__ rw2, const float* __restrict__ rb2,
    const float* __restrict__ ws, float* __restrict__ out) {
    __shared__ float s_sig[NS];  // per-sample sigma (0 if masked)
    __shared__ float s_w[NS];    // effective per-sample weights
    __shared__ int s_list[NS];   // active sample indices
    __shared__ float s_wsum[4];  // per-wave scan totals
    __shared__ float s_acc[4][3];
    __shared__ int s_cnt;

    const int ray = blockIdx.x;
    const int tid = threadIdx.x;
    const int f = tid & 63, wv = tid >> 6;
    if (tid == 0) s_cnt = 0;
    if (tid < NS) s_sig[tid] = 0.f;

    // ---- phase A: ray geometry + early slab rejection ----
    const float ox = ro[ray * 3 + 0], oy = ro[ray * 3 + 1],
                oz = ro[ray * 3 + 2];
    const float dx = rd[ray * 3 + 0], dy = rd[ray * 3 + 1],
                dz = rd[ray * 3 + 2];
    const float a0x = aabb[0], a0y = aabb[1], a0z = aabb[2];
    const float a1x = aabb[3], a1y = aabb[4], a1z = aabb[5];
    const float ex = a1x - a0x, ey = a1y - a0y, ez = a1z - a0z;
    const float step = sqrtf(ex * ex + ey * ey + ez * ez) / (float)NS;
    const float ddx = (dx == 0.f) ? dx + 1e-9f : dx;
    const float ddy = (dy == 0.f) ? dy + 1e-9f : dy;
    const float ddz = (dz == 0.f) ? dz + 1e-9f : dz;
    const float r1x = (a0x - ox) / ddx, r2x = (a1x - ox) / ddx;
    const float r1y = (a0y - oy) / ddy, r2y = (a1y - oy) / ddy;
    const float r1z = (a0z - oz) / ddz, r2z = (a1z - oz) / ddz;
    const float t_lo =
        fmaxf(fmaxf(fminf(r1x, r2x), fminf(r1y, r2y)), fminf(r1z, r2z));
    const float t_hi =
        fminf(fminf(fmaxf(r1x, r2x), fmaxf(r1y, r2y)), fmaxf(r1z, r2z));
    float t_min = fminf(fmaxf(t_lo, 0.f), 100000.f);
    // block-uniform early exit, one step of fp margin
    if (t_min > t_hi + step || t_min + 199.f * step < t_lo - step) {
        if (tid < 3) out[ray * 3 + tid] = 0.f;
        return;
    }

    // per-lane weight slices (lane = feature), h_j(t) = A_j + t*B_j
    const float wa = fw1[f], wb = fw1[64 + f], wc = fw1[128 + f];
    const float wd = fb1[f];
    const float we = ws[f];
    const float cbias = ws[FEAT];
    const float i2x = 2.f / ex, i2y = 2.f / ey, i2z = 2.f / ez;
    const float cx = (ox - a0x) * i2x - 1.f;
    const float cy = (oy - a0y) * i2y - 1.f;
    const float cz = (oz - a0z) * i2z - 1.f;
    const float gx = dx * i2x, gy = dy * i2y, gz = dz * i2z;
    const float Af = cx * wa + cy * wb + cz * wc + wd;
    const float Bf = gx * wa + gy * wb + gz * wc;

    // sample index range that can possibly be inside (±1 step margin)
    int s_begin = (int)floorf((t_lo - t_min) / step) - 1;
    if (s_begin < 0) s_begin = 0;
    int s_end = (int)ceilf((t_hi - t_min) / step) + 1;
    if (s_end > NS - 1) s_end = NS - 1;

    __syncthreads();  // s_sig init visible

    // ---- phase B: per-wave contiguous chunk, wave-uniform serial samples.
    // Grid reads are broadcast (one address per wave) and adjacent samples
    // share cache lines -> L2-friendly (round-3-proven locality pattern).
    const int span = s_end - s_begin + 1;
    const int chunk = (span + 3) >> 2;
    const int b0 = s_begin + wv * chunk;
    int b1 = b0 + chunk - 1;
    if (b1 > s_end) b1 = s_end;
    for (int s = b0; s <= b1; ++s) {
        float t = t_min + (float)s * step;
        float px = ox + dx * t, py = oy + dy * t, pz = oz + dz * t;
        bool inside = (px >= a0x) & (px <= a1x) & (py >= a0y) & (py <= a1y) &
                      (pz >= a0z) & (pz <= a1z);
        if (inside) {  // wave-uniform
            float scx = (px - a0x) / ex * 2.f - 1.f;
            float scy = (py - a0y) / ey * 2.f - 1.f;
            float scz = (pz - a0z) / ez * 2.f - 1.f;
            if (trilinear(gvol, scx, scy, scz) > 0.01f) {  // wave-uniform
                float p = fmaxf(Af + t * Bf, 0.f) * we;    // all 64 lanes
#pragma unroll
                for (int off = 32; off > 0; off >>= 1) p += __shfl_xor(p, off);
                if (f == 0) s_sig[s] = p + cbias;
            }
        }
    }
    __syncthreads();

    // ---- phase C: wave-level scan + cross-wave offsets ----
    float sig = (tid < NS) ? s_sig[tid] : 0.f;
    float la = -sig * step;
    float run = la;
#pragma unroll
    for (int off = 1; off < 64; off <<= 1) {
        float v = __shfl_up(run, off);
        if (f >= off) run += v;
    }
    if (f == 63) s_wsum[wv] = run;
    __syncthreads();
    float offs = 0.f;
    for (int k = 0; k < wv; ++k) offs += s_wsum[k];
    run += offs;
    if (tid < NS) {
        float trans = expf(run - la);  // prefix before this sample
        float e = expf(la);
        float w = (trans > 1e-4f) ? trans * (1.f - e) : 0.f;
        s_w[tid] = w;
        if (w != 0.f) {
            int p = atomicAdd(&s_cnt, 1);
            s_list[p] = tid;
        }
    }
    __syncthreads();
    const int cnt = s_cnt;
    if (cnt == 0) {
        if (tid < 3) out[ray * 3 + tid] = 0.f;
        return;
    }

    // ---- phase E: rgb head over compacted active samples ----
    const float fb2f = fb2[f];
    const float rh_dir = dx * rw1[64 * FEAT + f] + dy * rw1[65 * FEAT + f] +
                         dz * rw1[66 * FEAT + f] + rb1[f];
    const float w20 = rw2[f * 3 + 0], w21 = rw2[f * 3 + 1],
                w22 = rw2[f * 3 + 2];
    const float r20 = rb2[0], r21 = rb2[1], r22 = rb2[2];

    float a0 = 0.f, a1 = 0.f, a2 = 0.f;
    for (int i = wv; i < cnt; i += 4) {
        int s = s_list[i];
        float w_s = s_w[s];  // wave-uniform
        float t = t_min + (float)s * step;
        // h/fe computed by ALL 64 lanes (wave-uniform region) -> readlane safe
        float h = fmaxf(Af + t * Bf, 0.f);
        float e0 = 0.f, e1 = 0.f, e2 = 0.f, e3 = 0.f;
#pragma unroll
        for (int j = 0; j < FEAT; j += 4) {
            e0 += rl(h, j) * fw2[j * FEAT + f];
            e1 += rl(h, j + 1) * fw2[(j + 1) * FEAT + f];
            e2 += rl(h, j + 2) * fw2[(j + 2) * FEAT + f];
            e3 += rl(h, j + 3) * fw2[(j + 3) * FEAT + f];
        }
        float fe = fb2f + ((e0 + e1) + (e2 + e3));
        float g0 = 0.f, g1 = 0.f, g2 = 0.f, g3 = 0.f;
#pragma unroll
        for (int j = 0; j < FEAT; j += 4) {
            g0 += rl(fe, j) * rw1[j * FEAT + f];
            g1 += rl(fe, j + 1) * rw1[(j + 1) * FEAT + f];
            g2 += rl(fe, j + 2) * rw1[(j + 2) * FEAT + f];
            g3 += rl(fe, j + 3) * rw1[(j + 3) * FEAT + f];
        }
        float rh = fmaxf(rh_dir + ((g0 + g1) + (g2 + g3)), 0.f);
        float q0 = rh * w20, q1 = rh * w21, q2 = rh * w22;
#pragma unroll
        for (int off = 32; off > 0; off >>= 1) {
            q0 += __shfl_xor(q0, off);
            q1 += __shfl_xor(q1, off);
            q2 += __shfl_xor(q2, off);
        }
        a0 += w_s / (1.f + expf(-(q0 + r20)));
        a1 += w_s / (1.f + expf(-(q1 + r21)));
        a2 += w_s / (1.f + expf(-(q2 + r22)));
    }
    if (f == 0) {
        s_acc[wv][0] = a0;
        s_acc[wv][1] = a1;
        s_acc[wv][2] = a2;
    }
    __syncthreads();
    if (tid == 0) {
        out[ray * 3 + 0] =
            s_acc[0][0] + s_acc[1][0] + s_acc[2][0] + s_acc[3][0];
        out[ray * 3 + 1] =
            s_acc[0][1] + s_acc[1][1] + s_acc[2][1] + s_acc[3][1];
        out[ray * 3 + 2] =
            s_acc[0][2] + s_acc[1][2] + s_acc[2][2] + s_acc[3][2];
    }
}

extern "C" void kernel_launch(void* const* d_in, const int* in_sizes, int n_in,
                              void* d_out, int out_size, void* d_ws,
                              size_t ws_size, hipStream_t stream) {
    const float* rays_o = (const float*)d_in[0];
    const float* rays_d = (const float*)d_in[1];
    const float* grid = (const float*)d_in[2];
    const float* aabb = (const float*)d_in[3];
    const float* fw1 = (const float*)d_in[4];
    const float* fb1 = (const float*)d_in[5];
    const float* fw2 = (const float*)d_in[6];
    const float* fb2 = (const float*)d_in[7];
    const float* sw = (const float*)d_in[8];
    const float* sb = (const float*)d_in[9];
    const float* rw1 = (const float*)d_in[10];
    const float* rb1 = (const float*)d_in[11];
    const float* rw2 = (const float*)d_in[12];
    const float* rb2 = (const float*)d_in[13];
    float* out = (float*)d_out;
    float* ws = (float*)d_ws;
    const int n_rays = in_sizes[0] / 3;

    precomp<<<1, 128, 0, stream>>>(fw2, sw, fb2, sb, ws);
    render<<<n_rays, 256, 0, stream>>>(rays_o, rays_d, grid, aabb, fw1, fb1,
                                       fw2, fb2, rw1, rb1, rw2, rb2, ws, out);
}

// Round 9
// 237.645 us; speedup vs baseline: 3.7800x; 3.7800x over previous
//
#include <hip/hip_runtime.h>
#include <math.h>

#define NS 200
#define FEAT 64
#define GRIDN 128

__device__ __forceinline__ float rl(float v, int l) {
    return __uint_as_float(
        __builtin_amdgcn_readlane(__float_as_uint(v), (unsigned)l));
}

__device__ __forceinline__ float trilinear(const float* __restrict__ g,
                                           float x, float y, float z) {
    const float W = 128.f, H = 128.f, D = 128.f;
    float gx = ((x + 1.f) * W - 1.f) * 0.5f;
    float gy = ((y + 1.f) * H - 1.f) * 0.5f;
    float gz = ((z + 1.f) * D - 1.f) * 0.5f;
    float x0 = floorf(gx), y0 = floorf(gy), z0 = floorf(gz);
    float out = 0.f;
#pragma unroll
    for (int dz = 0; dz < 2; ++dz)
#pragma unroll
        for (int dy = 0; dy < 2; ++dy)
#pragma unroll
            for (int dx = 0; dx < 2; ++dx) {
                float xi = x0 + dx, yi = y0 + dy, zi = z0 + dz;
                float w = (1.f - fabsf(gx - xi)) * (1.f - fabsf(gy - yi)) *
                          (1.f - fabsf(gz - zi));
                bool valid = (xi >= 0.f) && (xi < W) && (yi >= 0.f) &&
                             (yi < H) && (zi >= 0.f) && (zi < D);
                int xc = (int)fminf(fmaxf(xi, 0.f), 127.f);
                int yc = (int)fminf(fmaxf(yi, 0.f), 127.f);
                int zc = (int)fminf(fmaxf(zi, 0.f), 127.f);
                float v = valid ? g[(zc * GRIDN + yc) * GRIDN + xc] : 0.f;
                out += w * v;
            }
    return out;
}

// ws usage: ONLY 65 floats. ws[0..63] = w2s = fw2@sw ; ws[64] = fb2@sw + sb
__global__ __launch_bounds__(128) void precomp(const float* __restrict__ fw2,
                                               const float* __restrict__ sw,
                                               const float* __restrict__ fb2,
                                               const float* __restrict__ sb,
                                               float* __restrict__ ws) {
    int tid = threadIdx.x;
    if (tid < FEAT) {
        float a = 0.f;
        for (int j = 0; j < FEAT; ++j) a += fw2[tid * FEAT + j] * sw[j];
        ws[tid] = a;
    } else if (tid == FEAT) {
        float a = sb[0];
        for (int j = 0; j < FEAT; ++j) a += fb2[j] * sw[j];
        ws[FEAT] = a;
    }
}

// NOTE: plain __launch_bounds__(256) — the (256,8) min-waves hint in rounds
// 7/8 squeezed VGPRs to 32 and caused scratch spills (105 MB WRITE_SIZE).
__global__ __launch_bounds__(256) void render(
    const float* __restrict__ ro, const float* __restrict__ rd,
    const float* __restrict__ gvol, const float* __restrict__ aabb,
    const float* __restrict__ fw1, const float* __restrict__ fb1,
    const float* __restrict__ fw2, const float* __restrict__ fb2,
    const float* __restrict__ rw1, const float* __restrict__ rb1,
    const float* __restrict__ rw2, const float* __restrict__ rb2,
    const float* __restrict__ ws, float* __restrict__ out) {
    __shared__ float s_sig[NS];  // per-sample sigma (0 if masked)
    __shared__ float s_w[NS];    // effective per-sample weights
    __shared__ int s_list[NS];   // active sample indices
    __shared__ float s_wsum[4];  // per-wave scan totals
    __shared__ float s_acc[4][3];
    __shared__ int s_cnt;

    const int ray = blockIdx.x;
    const int tid = threadIdx.x;
    const int f = tid & 63, wv = tid >> 6;
    if (tid == 0) s_cnt = 0;
    if (tid < NS) s_sig[tid] = 0.f;

    // ---- phase A: ray geometry + early slab rejection ----
    const float ox = ro[ray * 3 + 0], oy = ro[ray * 3 + 1],
                oz = ro[ray * 3 + 2];
    const float dx = rd[ray * 3 + 0], dy = rd[ray * 3 + 1],
                dz = rd[ray * 3 + 2];
    const float a0x = aabb[0], a0y = aabb[1], a0z = aabb[2];
    const float a1x = aabb[3], a1y = aabb[4], a1z = aabb[5];
    const float ex = a1x - a0x, ey = a1y - a0y, ez = a1z - a0z;
    const float step = sqrtf(ex * ex + ey * ey + ez * ez) / (float)NS;
    const float ddx = (dx == 0.f) ? dx + 1e-9f : dx;
    const float ddy = (dy == 0.f) ? dy + 1e-9f : dy;
    const float ddz = (dz == 0.f) ? dz + 1e-9f : dz;
    const float r1x = (a0x - ox) / ddx, r2x = (a1x - ox) / ddx;
    const float r1y = (a0y - oy) / ddy, r2y = (a1y - oy) / ddy;
    const float r1z = (a0z - oz) / ddz, r2z = (a1z - oz) / ddz;
    const float t_lo =
        fmaxf(fmaxf(fminf(r1x, r2x), fminf(r1y, r2y)), fminf(r1z, r2z));
    const float t_hi =
        fminf(fminf(fmaxf(r1x, r2x), fmaxf(r1y, r2y)), fmaxf(r1z, r2z));
    float t_min = fminf(fmaxf(t_lo, 0.f), 100000.f);
    // block-uniform early exit, one step of fp margin
    if (t_min > t_hi + step || t_min + 199.f * step < t_lo - step) {
        if (tid < 3) out[ray * 3 + tid] = 0.f;
        return;
    }

    // per-lane weight slices (lane = feature), h_j(t) = A_j + t*B_j
    const float wa = fw1[f], wb = fw1[64 + f], wc = fw1[128 + f];
    const float wd = fb1[f];
    const float we = ws[f];
    const float cbias = ws[FEAT];
    const float i2x = 2.f / ex, i2y = 2.f / ey, i2z = 2.f / ez;
    const float cx = (ox - a0x) * i2x - 1.f;
    const float cy = (oy - a0y) * i2y - 1.f;
    const float cz = (oz - a0z) * i2z - 1.f;
    const float gx = dx * i2x, gy = dy * i2y, gz = dz * i2z;
    const float Af = cx * wa + cy * wb + cz * wc + wd;
    const float Bf = gx * wa + gy * wb + gz * wc;

    // sample index range that can possibly be inside (±1 step margin)
    int s_begin = (int)floorf((t_lo - t_min) / step) - 1;
    if (s_begin < 0) s_begin = 0;
    int s_end = (int)ceilf((t_hi - t_min) / step) + 1;
    if (s_end > NS - 1) s_end = NS - 1;

    __syncthreads();  // s_sig init visible

    // ---- phase B: per-wave contiguous chunk, wave-uniform serial samples.
    // Grid reads are broadcast (one address per wave); adjacent samples
    // share cache lines -> L2-friendly (round-3-proven locality pattern).
    const int span = s_end - s_begin + 1;
    const int chunk = (span + 3) >> 2;
    const int b0 = s_begin + wv * chunk;
    int b1 = b0 + chunk - 1;
    if (b1 > s_end) b1 = s_end;
    for (int s = b0; s <= b1; ++s) {
        float t = t_min + (float)s * step;
        float px = ox + dx * t, py = oy + dy * t, pz = oz + dz * t;
        bool inside = (px >= a0x) & (px <= a1x) & (py >= a0y) & (py <= a1y) &
                      (pz >= a0z) & (pz <= a1z);
        if (inside) {  // wave-uniform
            float scx = (px - a0x) / ex * 2.f - 1.f;
            float scy = (py - a0y) / ey * 2.f - 1.f;
            float scz = (pz - a0z) / ez * 2.f - 1.f;
            if (trilinear(gvol, scx, scy, scz) > 0.01f) {  // wave-uniform
                float p = fmaxf(Af + t * Bf, 0.f) * we;    // all 64 lanes
#pragma unroll
                for (int off = 32; off > 0; off >>= 1) p += __shfl_xor(p, off);
                if (f == 0) s_sig[s] = p + cbias;
            }
        }
    }
    __syncthreads();

    // ---- phase C: wave-level scan + cross-wave offsets ----
    float sig = (tid < NS) ? s_sig[tid] : 0.f;
    float la = -sig * step;
    float run = la;
#pragma unroll
    for (int off = 1; off < 64; off <<= 1) {
        float v = __shfl_up(run, off);
        if (f >= off) run += v;
    }
    if (f == 63) s_wsum[wv] = run;
    __syncthreads();
    float offs = 0.f;
    for (int k = 0; k < wv; ++k) offs += s_wsum[k];
    run += offs;
    if (tid < NS) {
        float trans = expf(run - la);  // prefix before this sample
        float e = expf(la);
        float w = (trans > 1e-4f) ? trans * (1.f - e) : 0.f;
        s_w[tid] = w;
        if (w != 0.f) {
            int p = atomicAdd(&s_cnt, 1);
            s_list[p] = tid;
        }
    }
    __syncthreads();
    const int cnt = s_cnt;
    if (cnt == 0) {
        if (tid < 3) out[ray * 3 + tid] = 0.f;
        return;
    }

    // ---- phase E: rgb head over compacted active samples ----
    const float fb2f = fb2[f];
    const float rh_dir = dx * rw1[64 * FEAT + f] + dy * rw1[65 * FEAT + f] +
                         dz * rw1[66 * FEAT + f] + rb1[f];
    const float w20 = rw2[f * 3 + 0], w21 = rw2[f * 3 + 1],
                w22 = rw2[f * 3 + 2];
    const float r20 = rb2[0], r21 = rb2[1], r22 = rb2[2];

    float a0 = 0.f, a1 = 0.f, a2 = 0.f;
    for (int i = wv; i < cnt; i += 4) {
        int s = s_list[i];
        float w_s = s_w[s];  // wave-uniform
        float t = t_min + (float)s * step;
        // h/fe computed by ALL 64 lanes (wave-uniform region) -> readlane safe
        float h = fmaxf(Af + t * Bf, 0.f);
        float e0 = 0.f, e1 = 0.f, e2 = 0.f, e3 = 0.f;
#pragma unroll 4  // bounded unroll: 16 in-flight loads, no spill pressure
        for (int j = 0; j < FEAT; j += 4) {
            e0 += rl(h, j) * fw2[j * FEAT + f];
            e1 += rl(h, j + 1) * fw2[(j + 1) * FEAT + f];
            e2 += rl(h, j + 2) * fw2[(j + 2) * FEAT + f];
            e3 += rl(h, j + 3) * fw2[(j + 3) * FEAT + f];
        }
        float fe = fb2f + ((e0 + e1) + (e2 + e3));
        float g0 = 0.f, g1 = 0.f, g2 = 0.f, g3 = 0.f;
#pragma unroll 4
        for (int j = 0; j < FEAT; j += 4) {
            g0 += rl(fe, j) * rw1[j * FEAT + f];
            g1 += rl(fe, j + 1) * rw1[(j + 1) * FEAT + f];
            g2 += rl(fe, j + 2) * rw1[(j + 2) * FEAT + f];
            g3 += rl(fe, j + 3) * rw1[(j + 3) * FEAT + f];
        }
        float rh = fmaxf(rh_dir + ((g0 + g1) + (g2 + g3)), 0.f);
        float q0 = rh * w20, q1 = rh * w21, q2 = rh * w22;
#pragma unroll
        for (int off = 32; off > 0; off >>= 1) {
            q0 += __shfl_xor(q0, off);
            q1 += __shfl_xor(q1, off);
            q2 += __shfl_xor(q2, off);
        }
        a0 += w_s / (1.f + expf(-(q0 + r20)));
        a1 += w_s / (1.f + expf(-(q1 + r21)));
        a2 += w_s / (1.f + expf(-(q2 + r22)));
    }
    if (f == 0) {
        s_acc[wv][0] = a0;
        s_acc[wv][1] = a1;
        s_acc[wv][2] = a2;
    }
    __syncthreads();
    if (tid == 0) {
        out[ray * 3 + 0] =
            s_acc[0][0] + s_acc[1][0] + s_acc[2][0] + s_acc[3][0];
        out[ray * 3 + 1] =
            s_acc[0][1] + s_acc[1][1] + s_acc[2][1] + s_acc[3][1];
        out[ray * 3 + 2] =
            s_acc[0][2] + s_acc[1][2] + s_acc[2][2] + s_acc[3][2];
    }
}

extern "C" void kernel_launch(void* const* d_in, const int* in_sizes, int n_in,
                              void* d_out, int out_size, void* d_ws,
                              size_t ws_size, hipStream_t stream) {
    const float* rays_o = (const float*)d_in[0];
    const float* rays_d = (const float*)d_in[1];
    const float* grid = (const float*)d_in[2];
    const float* aabb = (const float*)d_in[3];
    const float* fw1 = (const float*)d_in[4];
    const float* fb1 = (const float*)d_in[5];
    const float* fw2 = (const float*)d_in[6];
    const float* fb2 = (const float*)d_in[7];
    const float* sw = (const float*)d_in[8];
    const float* sb = (const float*)d_in[9];
    const float* rw1 = (const float*)d_in[10];
    const float* rb1 = (const float*)d_in[11];
    const float* rw2 = (const float*)d_in[12];
    const float* rb2 = (const float*)d_in[13];
    float* out = (float*)d_out;
    float* ws = (float*)d_ws;
    const int n_rays = in_sizes[0] / 3;

    precomp<<<1, 128, 0, stream>>>(fw2, sw, fb2, sb, ws);
    render<<<n_rays, 256, 0, stream>>>(rays_o, rays_d, grid, aabb, fw1, fb1,
                                       fw2, fb2, rw1, rb1, rw2, rb2, ws, out);
}